// Round 5
// baseline (346.782 us; speedup 1.0000x reference)
//
#include <hip/hip_runtime.h>
#include <hip/hip_bf16.h>

constexpr int FDIM = 128;

typedef __attribute__((ext_vector_type(8))) short bf16x8;   // 8 bf16 = 4 VGPRs
typedef __attribute__((ext_vector_type(4))) float f32x4;

static __device__ __forceinline__ ushort f2bf(float f){
    union { float f; unsigned u; } v; v.f = f;
    unsigned r = v.u + 0x7fffu + ((v.u >> 16) & 1u);   // RNE
    return (ushort)(r >> 16);
}
static __device__ __forceinline__ float bfhi(unsigned u){
    union { unsigned u; float f; } c; c.u = u & 0xffff0000u; return c.f;
}
static __device__ __forceinline__ float bflo(unsigned u){
    union { unsigned u; float f; } c; c.u = u << 16; return c.f;
}

// ---------------- CSR build ----------------

__global__ __launch_bounds__(256) void k_degree_rank(const int* __restrict__ dst, int* __restrict__ deg,
                                                     int* __restrict__ rank, int E){
    int e = blockIdx.x*256 + threadIdx.x;
    if (e < E) rank[e] = atomicAdd(&deg[dst[e]], 1);
}

__global__ __launch_bounds__(256) void k_scan1(const int* __restrict__ deg, int* __restrict__ partial,
                                               int* __restrict__ bsum, int N){
    __shared__ int s[256];
    int i = blockIdx.x*256 + threadIdx.x;
    int v = (i < N) ? deg[i] : 0;
    s[threadIdx.x] = v;
    __syncthreads();
    for (int ofs = 1; ofs < 256; ofs <<= 1){
        int add = (threadIdx.x >= ofs) ? s[threadIdx.x - ofs] : 0;
        __syncthreads();
        s[threadIdx.x] += add;
        __syncthreads();
    }
    if (i < N) partial[i] = s[threadIdx.x];
    if (threadIdx.x == 255) bsum[blockIdx.x] = s[255];
}

__global__ __launch_bounds__(256) void k_scan2(int* __restrict__ bsum, int nb){
    __shared__ int s[256];
    int t = threadIdx.x;
    int v = (t < nb) ? bsum[t] : 0;
    s[t] = v;
    __syncthreads();
    for (int ofs = 1; ofs < 256; ofs <<= 1){
        int add = (t >= ofs) ? s[t - ofs] : 0;
        __syncthreads();
        s[t] += add;
        __syncthreads();
    }
    if (t < nb) bsum[t] = s[t] - v;   // exclusive
}

__global__ __launch_bounds__(256) void k_scan3(const int* __restrict__ partial, const int* __restrict__ deg,
                                               const int* __restrict__ bsum, int* __restrict__ off, int N){
    int i = blockIdx.x*256 + threadIdx.x;
    if (i < N) off[i] = partial[i] - deg[i] + bsum[blockIdx.x];
}

// windowed fill (R4 win: kills 64B-line write amplification; window->XCD affinity heuristic)
__global__ __launch_bounds__(256) void k_fill_win(const int* __restrict__ src, const int* __restrict__ dst,
                                                  const int* __restrict__ rank, const int* __restrict__ off,
                                                  int* __restrict__ csr, int E, int WINW){
    const int win   = blockIdx.x & 7;
    const int slice = blockIdx.x >> 3;
    const int lo = win * WINW, hi = lo + WINW;
    const int ES = (E + 63) >> 6;
    const int e0 = slice * ES, e1 = min(E, e0 + ES);
    for (int e = e0 + (int)threadIdx.x; e < e1; e += 256){
        int d = dst[e];
        if (d >= lo && d < hi)
            csr[off[d] + rank[e]] = src[e];
    }
}

// ---------------- fp32 -> bf16 casts ----------------

__global__ __launch_bounds__(256) void k_cast_bf16(const float* __restrict__ src, ushort* __restrict__ dst, int n){
    int i4 = (blockIdx.x*256 + threadIdx.x) * 4;
    if (i4 < n){
        float4 v = *(const float4*)(src + i4);
        ushort4 o; o.x=f2bf(v.x); o.y=f2bf(v.y); o.z=f2bf(v.z); o.w=f2bf(v.w);
        *(ushort4*)(dst + i4) = o;
    }
}

__global__ __launch_bounds__(256) void k_build_w3(
    const float* __restrict__ W1_l, const float* __restrict__ W1_r,
    const float* __restrict__ Wl1,
    const float* __restrict__ W2_l, const float* __restrict__ W2_r,
    ushort* __restrict__ Wb1, ushort* __restrict__ Wbm, ushort* __restrict__ Wb2)
{
    int i = blockIdx.x*256 + threadIdx.x;   // grid = 320 blocks
    int row = i >> 8, k = i & 255;
    float v; ushort* d;
    if (row < 128){
        int n = row;
        v = (k < 128) ? W1_l[(size_t)n*128 + k] : W1_r[(size_t)n*128 + k - 128];
        d = Wb1 + (size_t)n*256 + k;
    } else if (row < 256){
        int n = row - 128;
        v = Wl1[(size_t)n*256 + k];
        d = Wbm + (size_t)n*256 + k;
    } else {
        int n = row - 256;
        v = (k < 128) ? W2_l[(size_t)n*128 + k] : W2_r[(size_t)n*128 + k - 128];
        d = Wb2 + (size_t)n*256 + k;
    }
    *d = f2bf(v);
}

// ---------------- shared building blocks for the fused kernels ----------------

// aggregate 16 nodes [wbase, wbase+16) into Sw (wave-private LDS, bf16, pad 136)
static __device__ __forceinline__ void wave_aggregate16(
    const ushort* __restrict__ feat, const int* __restrict__ csr,
    const int* __restrict__ off, const int* __restrict__ deg,
    ushort (*Sw)[136], int wbase, int lane, int N)
{
    const int grp = lane >> 4;        // edge slot within quad of edges
    const int sub = lane & 15;        // 16B column chunk
    for (int n = 0; n < 16; n++){
        int node = wbase + n;
        int o = 0, d = 0;
        if (node < N){ o = off[node]; d = deg[node]; }
        float a0=0.f,a1=0.f,a2=0.f,a3=0.f,a4=0.f,a5=0.f,a6=0.f,a7=0.f;
        for (int base = 0; base < d; base += 64){
            int cnt = min(64, d - base);
            int idx = (lane < cnt) ? csr[o + base + lane] : -1;
            int iters = (cnt + 3) >> 2;
            #pragma unroll 4
            for (int j = 0; j < iters; j++){
                int s = __shfl(idx, j*4 + grp);
                unsigned msk = (s >= 0) ? 0xffffffffu : 0u;
                int sr = (s >= 0) ? s : 0;
                uint4 raw = *(const uint4*)(feat + (size_t)sr*FDIM + sub*8);
                raw.x &= msk; raw.y &= msk; raw.z &= msk; raw.w &= msk;
                a0 += bflo(raw.x); a1 += bfhi(raw.x);
                a2 += bflo(raw.y); a3 += bfhi(raw.y);
                a4 += bflo(raw.z); a5 += bfhi(raw.z);
                a6 += bflo(raw.w); a7 += bfhi(raw.w);
            }
        }
        a0 += __shfl_xor(a0,16); a1 += __shfl_xor(a1,16); a2 += __shfl_xor(a2,16); a3 += __shfl_xor(a3,16);
        a4 += __shfl_xor(a4,16); a5 += __shfl_xor(a5,16); a6 += __shfl_xor(a6,16); a7 += __shfl_xor(a7,16);
        a0 += __shfl_xor(a0,32); a1 += __shfl_xor(a1,32); a2 += __shfl_xor(a2,32); a3 += __shfl_xor(a3,32);
        a4 += __shfl_xor(a4,32); a5 += __shfl_xor(a5,32); a6 += __shfl_xor(a6,32); a7 += __shfl_xor(a7,32);
        if (grp == 0){
            float inv = 1.f / (float)(d > 1 ? d : 1);
            uint4 r;
            r.x = (unsigned)f2bf(a0*inv) | ((unsigned)f2bf(a1*inv) << 16);
            r.y = (unsigned)f2bf(a2*inv) | ((unsigned)f2bf(a3*inv) << 16);
            r.z = (unsigned)f2bf(a4*inv) | ((unsigned)f2bf(a5*inv) << 16);
            r.w = (unsigned)f2bf(a6*inv) | ((unsigned)f2bf(a7*inv) << 16);
            *(uint4*)&Sw[n][sub*8] = r;
        }
    }
}

// ---------------- fused layer 1 + mid: agg(x) -> lin1(norm,relu) -> mid(relu) -> hb ----------------
// 256 thr = 4 independent waves, 16 nodes each. LDS Sw holds agg, then is reused for h1.

__global__ __launch_bounds__(256) void k_fusedA(
    const ushort* __restrict__ xb, const int* __restrict__ csr,
    const int* __restrict__ off, const int* __restrict__ deg,
    const ushort* __restrict__ Wb1, const float* __restrict__ b1,
    const ushort* __restrict__ Wbm, const float* __restrict__ bm,
    ushort* __restrict__ hb, int N)
{
    __shared__ __align__(16) ushort S[4][16][136];   // 17.4 KB
    const int wave = threadIdx.x >> 6, lane = threadIdx.x & 63;
    const int wbase = blockIdx.x*64 + wave*16;
    ushort (*Sw)[136] = S[wave];

    wave_aggregate16(xb, csr, off, deg, Sw, wbase, lane, N);
    __syncthreads();

    // ---- lin1: [agg | x] @ Wb1^T ----
    const int m = lane & 15, quad = lane >> 4;
    int r = wbase + m; if (r >= N) r = N - 1;
    const ushort* xp  = xb  + (size_t)r*FDIM + quad*8;
    const ushort* w1p = Wb1 + (size_t)m*256 + quad*8;
    f32x4 acc[8];
    #pragma unroll
    for (int nt = 0; nt < 8; nt++) acc[nt] = f32x4{0.f,0.f,0.f,0.f};
    #pragma unroll
    for (int kt = 0; kt < 8; kt++){
        const int kk = kt*32;
        bf16x8 af = (kk < 128) ? *(const bf16x8*)&Sw[m][kk + quad*8]
                               : *(const bf16x8*)(xp + (kk - 128));
        #pragma unroll
        for (int nt = 0; nt < 8; nt++){
            bf16x8 bfr = *(const bf16x8*)(w1p + (size_t)nt*16*256 + kk);
            acc[nt] = __builtin_amdgcn_mfma_f32_16x16x32_bf16(af, bfr, acc[nt], 0, 0, 0);
        }
    }
    // bias + L2-norm + relu
    #pragma unroll
    for (int nt = 0; nt < 8; nt++){
        float b = b1[nt*16 + m];
        acc[nt][0]+=b; acc[nt][1]+=b; acc[nt][2]+=b; acc[nt][3]+=b;
    }
    #pragma unroll
    for (int reg = 0; reg < 4; reg++){
        float ss = 0.f;
        #pragma unroll
        for (int nt = 0; nt < 8; nt++) ss += acc[nt][reg]*acc[nt][reg];
        ss += __shfl_xor(ss,1); ss += __shfl_xor(ss,2); ss += __shfl_xor(ss,4); ss += __shfl_xor(ss,8);
        float invn = 1.f / fmaxf(sqrtf(ss), 1e-12f);
        #pragma unroll
        for (int nt = 0; nt < 8; nt++) acc[nt][reg] = fmaxf(acc[nt][reg]*invn, 0.f);
    }

    __syncthreads();   // all lin1 LDS reads done before overwrite
    // write h1 (C-layout) into Sw as [row][col] bf16
    #pragma unroll
    for (int reg = 0; reg < 4; reg++){
        int row = quad*4 + reg;
        #pragma unroll
        for (int nt = 0; nt < 8; nt++) Sw[row][m + nt*16] = f2bf(acc[nt][reg]);
    }
    __syncthreads();

    // ---- mid: [x | h1] @ Wbm^T, relu ----
    const ushort* wmp = Wbm + (size_t)m*256 + quad*8;
    f32x4 acc2[8];
    #pragma unroll
    for (int nt = 0; nt < 8; nt++) acc2[nt] = f32x4{0.f,0.f,0.f,0.f};
    #pragma unroll
    for (int kt = 0; kt < 8; kt++){
        const int kk = kt*32;
        bf16x8 af = (kk < 128) ? *(const bf16x8*)(xp + kk)
                               : *(const bf16x8*)&Sw[m][(kk - 128) + quad*8];
        #pragma unroll
        for (int nt = 0; nt < 8; nt++){
            bf16x8 bfr = *(const bf16x8*)(wmp + (size_t)nt*16*256 + kk);
            acc2[nt] = __builtin_amdgcn_mfma_f32_16x16x32_bf16(af, bfr, acc2[nt], 0, 0, 0);
        }
    }
    #pragma unroll
    for (int reg = 0; reg < 4; reg++){
        int row = wbase + quad*4 + reg;
        if (row < N){
            ushort* o = hb + (size_t)row*FDIM + m;
            #pragma unroll
            for (int nt = 0; nt < 8; nt++){
                float v = fmaxf(acc2[nt][reg] + bm[nt*16 + m], 0.f);
                o[nt*16] = f2bf(v);
            }
        }
    }
}

// ---------------- fused layer 2: agg(h) -> lin2(norm) -> out (fp32) ----------------

__global__ __launch_bounds__(256) void k_fusedB(
    const ushort* __restrict__ hb, const int* __restrict__ csr,
    const int* __restrict__ off, const int* __restrict__ deg,
    const ushort* __restrict__ Wb2, const float* __restrict__ b2,
    float* __restrict__ out, int N)
{
    __shared__ __align__(16) ushort S[4][16][136];
    const int wave = threadIdx.x >> 6, lane = threadIdx.x & 63;
    const int wbase = blockIdx.x*64 + wave*16;
    ushort (*Sw)[136] = S[wave];

    wave_aggregate16(hb, csr, off, deg, Sw, wbase, lane, N);
    __syncthreads();

    const int m = lane & 15, quad = lane >> 4;
    int r = wbase + m; if (r >= N) r = N - 1;
    const ushort* hp  = hb  + (size_t)r*FDIM + quad*8;
    const ushort* w2p = Wb2 + (size_t)m*256 + quad*8;
    f32x4 acc[4];
    #pragma unroll
    for (int nt = 0; nt < 4; nt++) acc[nt] = f32x4{0.f,0.f,0.f,0.f};
    #pragma unroll
    for (int kt = 0; kt < 8; kt++){
        const int kk = kt*32;
        bf16x8 af = (kk < 128) ? *(const bf16x8*)&Sw[m][kk + quad*8]
                               : *(const bf16x8*)(hp + (kk - 128));
        #pragma unroll
        for (int nt = 0; nt < 4; nt++){
            bf16x8 bfr = *(const bf16x8*)(w2p + (size_t)nt*16*256 + kk);
            acc[nt] = __builtin_amdgcn_mfma_f32_16x16x32_bf16(af, bfr, acc[nt], 0, 0, 0);
        }
    }
    #pragma unroll
    for (int nt = 0; nt < 4; nt++){
        float b = b2[nt*16 + m];
        acc[nt][0]+=b; acc[nt][1]+=b; acc[nt][2]+=b; acc[nt][3]+=b;
    }
    #pragma unroll
    for (int reg = 0; reg < 4; reg++){
        float ss = 0.f;
        #pragma unroll
        for (int nt = 0; nt < 4; nt++) ss += acc[nt][reg]*acc[nt][reg];
        ss += __shfl_xor(ss,1); ss += __shfl_xor(ss,2); ss += __shfl_xor(ss,4); ss += __shfl_xor(ss,8);
        float invn = 1.f / fmaxf(sqrtf(ss), 1e-12f);
        int row = wbase + quad*4 + reg;
        if (row < N){
            float* o = out + (size_t)row*64 + m;
            #pragma unroll
            for (int nt = 0; nt < 4; nt++) o[nt*16] = acc[nt][reg]*invn;
        }
    }
}

// ---------------- launch ----------------

extern "C" void kernel_launch(void* const* d_in, const int* in_sizes, int n_in,
                              void* d_out, int out_size, void* d_ws, size_t ws_size,
                              hipStream_t stream)
{
    const float* x    = (const float*)d_in[0];
    const int*   ei   = (const int*)  d_in[1];
    const float* W1_l = (const float*)d_in[2];
    const float* b1_l = (const float*)d_in[3];
    const float* W1_r = (const float*)d_in[4];
    const float* Wl1  = (const float*)d_in[5];
    const float* bl1  = (const float*)d_in[6];
    const float* W2_l = (const float*)d_in[7];
    const float* b2_l = (const float*)d_in[8];
    const float* W2_r = (const float*)d_in[9];
    float* out = (float*)d_out;

    const int N = in_sizes[0] / FDIM;   // 50000
    const int E = in_sizes[1] / 2;      // 800000

    const int* src = ei;
    const int* dst = ei + E;

    char* p = (char*)d_ws;
    auto carve = [&](size_t bytes) -> void* {
        void* r = (void*)p;
        p += (bytes + 255) & ~(size_t)255;
        return r;
    };
    int*    deg     = (int*)   carve((size_t)N * 4);
    int*    partial = (int*)   carve((size_t)N * 4);
    int*    bsum    = (int*)   carve(256 * 4);
    int*    off     = (int*)   carve((size_t)N * 4);
    int*    rank    = (int*)   carve((size_t)E * 4);
    int*    csr     = (int*)   carve((size_t)E * 4);
    ushort* xb      = (ushort*)carve((size_t)N * FDIM * 2);
    ushort* hb      = (ushort*)carve((size_t)N * FDIM * 2);
    ushort* Wb1     = (ushort*)carve((size_t)128 * 256 * 2);
    ushort* Wbm     = (ushort*)carve((size_t)128 * 256 * 2);
    ushort* Wb2     = (ushort*)carve((size_t)64  * 256 * 2);

    hipMemsetAsync(deg, 0, (size_t)N * 4, stream);

    const int gE    = (E + 255) / 256;
    const int gN    = (N + 255) / 256;
    const int gFus  = (N + 63) / 64;                  // 4 waves x 16 nodes
    const int gCast = (N * FDIM / 4 + 255) / 256;
    const int WINW  = (N + 7) / 8;

    // CSR build (reused by both aggregations)
    k_degree_rank<<<gE, 256, 0, stream>>>(dst, deg, rank, E);
    k_scan1 <<<gN, 256, 0, stream>>>(deg, partial, bsum, N);
    k_scan2 <<<1,  256, 0, stream>>>(bsum, gN);
    k_scan3 <<<gN, 256, 0, stream>>>(partial, deg, bsum, off, N);
    k_fill_win<<<512, 256, 0, stream>>>(src, dst, rank, off, csr, E, WINW);

    // bf16 conversions
    k_cast_bf16<<<gCast, 256, 0, stream>>>(x, xb, N * FDIM);
    k_build_w3<<<320, 256, 0, stream>>>(W1_l, W1_r, Wl1, W2_l, W2_r, Wb1, Wbm, Wb2);

    // fused layer1 + mid, then fused layer2
    k_fusedA<<<gFus, 256, 0, stream>>>(xb, csr, off, deg, Wb1, b1_l, Wbm, bl1, hb, N);
    k_fusedB<<<gFus, 256, 0, stream>>>(hb, csr, off, deg, Wb2, b2_l, out, N);
}

// Round 6
// 309.728 us; speedup vs baseline: 1.1196x; 1.1196x over previous
//
#include <hip/hip_runtime.h>
#include <hip/hip_bf16.h>

constexpr int FDIM = 128;

typedef __attribute__((ext_vector_type(8))) short bf16x8;   // 8 bf16 = 4 VGPRs
typedef __attribute__((ext_vector_type(4))) float f32x4;

static __device__ __forceinline__ ushort f2bf(float f){
    union { float f; unsigned u; } v; v.f = f;
    unsigned r = v.u + 0x7fffu + ((v.u >> 16) & 1u);   // RNE
    return (ushort)(r >> 16);
}
static __device__ __forceinline__ float bfhi(unsigned u){
    union { unsigned u; float f; } c; c.u = u & 0xffff0000u; return c.f;
}
static __device__ __forceinline__ float bflo(unsigned u){
    union { unsigned u; float f; } c; c.u = u << 16; return c.f;
}

// ---------------- CSR build ----------------

__global__ __launch_bounds__(256) void k_degree_rank(const int* __restrict__ dst, int* __restrict__ deg,
                                                     int* __restrict__ rank, int E){
    int e = blockIdx.x*256 + threadIdx.x;
    if (e < E) rank[e] = atomicAdd(&deg[dst[e]], 1);
}

__global__ __launch_bounds__(256) void k_scan1(const int* __restrict__ deg, int* __restrict__ partial,
                                               int* __restrict__ bsum, int N){
    __shared__ int s[256];
    int i = blockIdx.x*256 + threadIdx.x;
    int v = (i < N) ? deg[i] : 0;
    s[threadIdx.x] = v;
    __syncthreads();
    for (int ofs = 1; ofs < 256; ofs <<= 1){
        int add = (threadIdx.x >= ofs) ? s[threadIdx.x - ofs] : 0;
        __syncthreads();
        s[threadIdx.x] += add;
        __syncthreads();
    }
    if (i < N) partial[i] = s[threadIdx.x];
    if (threadIdx.x == 255) bsum[blockIdx.x] = s[255];
}

__global__ __launch_bounds__(256) void k_scan2(int* __restrict__ bsum, int nb){
    __shared__ int s[256];
    int t = threadIdx.x;
    int v = (t < nb) ? bsum[t] : 0;
    s[t] = v;
    __syncthreads();
    for (int ofs = 1; ofs < 256; ofs <<= 1){
        int add = (t >= ofs) ? s[t - ofs] : 0;
        __syncthreads();
        s[t] += add;
        __syncthreads();
    }
    if (t < nb) bsum[t] = s[t] - v;   // exclusive
}

__global__ __launch_bounds__(256) void k_scan3(const int* __restrict__ partial, const int* __restrict__ deg,
                                               const int* __restrict__ bsum, int* __restrict__ off, int N){
    int i = blockIdx.x*256 + threadIdx.x;
    if (i < N) off[i] = partial[i] - deg[i] + bsum[blockIdx.x];
}

// windowed fill (R4 win: kills 64B-line write amplification; window->XCD affinity heuristic)
__global__ __launch_bounds__(256) void k_fill_win(const int* __restrict__ src, const int* __restrict__ dst,
                                                  const int* __restrict__ rank, const int* __restrict__ off,
                                                  int* __restrict__ csr, int E, int WINW){
    const int win   = blockIdx.x & 7;
    const int slice = blockIdx.x >> 3;
    const int lo = win * WINW, hi = lo + WINW;
    const int ES = (E + 63) >> 6;
    const int e0 = slice * ES, e1 = min(E, e0 + ES);
    for (int e = e0 + (int)threadIdx.x; e < e1; e += 256){
        int d = dst[e];
        if (d >= lo && d < hi)
            csr[off[d] + rank[e]] = src[e];
    }
}

// ---------------- fp32 -> bf16 casts ----------------

__global__ __launch_bounds__(256) void k_cast_bf16(const float* __restrict__ src, ushort* __restrict__ dst, int n){
    int i4 = (blockIdx.x*256 + threadIdx.x) * 4;
    if (i4 < n){
        float4 v = *(const float4*)(src + i4);
        ushort4 o; o.x=f2bf(v.x); o.y=f2bf(v.y); o.z=f2bf(v.z); o.w=f2bf(v.w);
        *(ushort4*)(dst + i4) = o;
    }
}

__global__ __launch_bounds__(256) void k_build_w3(
    const float* __restrict__ W1_l, const float* __restrict__ W1_r,
    const float* __restrict__ Wl1,
    const float* __restrict__ W2_l, const float* __restrict__ W2_r,
    ushort* __restrict__ Wb1, ushort* __restrict__ Wbm, ushort* __restrict__ Wb2)
{
    int i = blockIdx.x*256 + threadIdx.x;   // grid = 320 blocks
    int row = i >> 8, k = i & 255;
    float v; ushort* d;
    if (row < 128){
        int n = row;
        v = (k < 128) ? W1_l[(size_t)n*128 + k] : W1_r[(size_t)n*128 + k - 128];
        d = Wb1 + (size_t)n*256 + k;
    } else if (row < 256){
        int n = row - 128;
        v = Wl1[(size_t)n*256 + k];
        d = Wbm + (size_t)n*256 + k;
    } else {
        int n = row - 256;
        v = (k < 128) ? W2_l[(size_t)n*128 + k] : W2_r[(size_t)n*128 + k - 128];
        d = Wb2 + (size_t)n*256 + k;
    }
    *d = f2bf(v);
}

// ---------------- mean aggregation: one wave per node, 16 edges in flight ----------------
// Wave = 4 groups x 16 lanes; group g covers edge 4j+g with a 16B (8-col) load per lane.
// 4-deep explicit pipeline: 4 gathers issued before any unpack -> 4x memory-level parallelism.

__global__ __launch_bounds__(256) void k_aggregate_bf16(
    const ushort* __restrict__ feat, const int* __restrict__ csr,
    const int* __restrict__ off, const int* __restrict__ deg,
    ushort* __restrict__ agg, int N)
{
    int node = (blockIdx.x*256 + threadIdx.x) >> 6;
    int lane = threadIdx.x & 63;
    if (node >= N) return;
    const int grp = lane >> 4;
    const int sub = lane & 15;
    int o = off[node], d = deg[node];

    float a0=0.f,a1=0.f,a2=0.f,a3=0.f,a4=0.f,a5=0.f,a6=0.f,a7=0.f;

    auto accum = [&](uint4 r){
        a0 += bflo(r.x); a1 += bfhi(r.x);
        a2 += bflo(r.y); a3 += bfhi(r.y);
        a4 += bflo(r.z); a5 += bfhi(r.z);
        a6 += bflo(r.w); a7 += bfhi(r.w);
    };

    for (int base = 0; base < d; base += 64){
        int cnt = min(64, d - base);
        int idx = (lane < cnt) ? csr[o + base + lane] : -1;
        int iters = (cnt + 3) >> 2;
        int j = 0;
        for (; j + 4 <= iters; j += 4){
            int s0 = __shfl(idx, (j+0)*4 + grp);
            int s1 = __shfl(idx, (j+1)*4 + grp);
            int s2 = __shfl(idx, (j+2)*4 + grp);
            int s3 = __shfl(idx, (j+3)*4 + grp);
            unsigned m0 = (s0 >= 0) ? 0xffffffffu : 0u;  int p0 = (s0 >= 0) ? s0 : 0;
            unsigned m1 = (s1 >= 0) ? 0xffffffffu : 0u;  int p1 = (s1 >= 0) ? s1 : 0;
            unsigned m2 = (s2 >= 0) ? 0xffffffffu : 0u;  int p2 = (s2 >= 0) ? s2 : 0;
            unsigned m3 = (s3 >= 0) ? 0xffffffffu : 0u;  int p3 = (s3 >= 0) ? s3 : 0;
            uint4 r0 = *(const uint4*)(feat + (size_t)p0*FDIM + sub*8);
            uint4 r1 = *(const uint4*)(feat + (size_t)p1*FDIM + sub*8);
            uint4 r2 = *(const uint4*)(feat + (size_t)p2*FDIM + sub*8);
            uint4 r3 = *(const uint4*)(feat + (size_t)p3*FDIM + sub*8);
            r0.x &= m0; r0.y &= m0; r0.z &= m0; r0.w &= m0;
            r1.x &= m1; r1.y &= m1; r1.z &= m1; r1.w &= m1;
            r2.x &= m2; r2.y &= m2; r2.z &= m2; r2.w &= m2;
            r3.x &= m3; r3.y &= m3; r3.z &= m3; r3.w &= m3;
            accum(r0); accum(r1); accum(r2); accum(r3);
        }
        for (; j < iters; j++){
            int s = __shfl(idx, j*4 + grp);
            unsigned msk = (s >= 0) ? 0xffffffffu : 0u;
            int sr = (s >= 0) ? s : 0;
            uint4 raw = *(const uint4*)(feat + (size_t)sr*FDIM + sub*8);
            raw.x &= msk; raw.y &= msk; raw.z &= msk; raw.w &= msk;
            accum(raw);
        }
    }

    a0 += __shfl_xor(a0,16); a1 += __shfl_xor(a1,16); a2 += __shfl_xor(a2,16); a3 += __shfl_xor(a3,16);
    a4 += __shfl_xor(a4,16); a5 += __shfl_xor(a5,16); a6 += __shfl_xor(a6,16); a7 += __shfl_xor(a7,16);
    a0 += __shfl_xor(a0,32); a1 += __shfl_xor(a1,32); a2 += __shfl_xor(a2,32); a3 += __shfl_xor(a3,32);
    a4 += __shfl_xor(a4,32); a5 += __shfl_xor(a5,32); a6 += __shfl_xor(a6,32); a7 += __shfl_xor(a7,32);

    if (grp == 0){
        float inv = 1.f / (float)(d > 1 ? d : 1);
        uint4 r;
        r.x = (unsigned)f2bf(a0*inv) | ((unsigned)f2bf(a1*inv) << 16);
        r.y = (unsigned)f2bf(a2*inv) | ((unsigned)f2bf(a3*inv) << 16);
        r.z = (unsigned)f2bf(a4*inv) | ((unsigned)f2bf(a5*inv) << 16);
        r.w = (unsigned)f2bf(a6*inv) | ((unsigned)f2bf(a7*inv) << 16);
        *(uint4*)(agg + (size_t)node*FDIM + sub*8) = r;
    }
}

// ---------------- fused lin1 + mid (row-local, no gather): 4 waves x 16 rows ----------------
// h1 = relu(norm([agg|x] @ Wb1^T + b1));  hb = relu([x|h1] @ Wbm^T + bm)
// h1 lives only in wave-private LDS. No early return (uniform barriers); loads clamped, stores masked.

__global__ __launch_bounds__(256) void k_lin1mid(
    const ushort* __restrict__ aggb, const ushort* __restrict__ xb,
    const ushort* __restrict__ Wb1, const float* __restrict__ b1,
    const ushort* __restrict__ Wbm, const float* __restrict__ bm,
    ushort* __restrict__ hb, int N)
{
    __shared__ __align__(16) ushort S[4][16][136];   // 17.4 KB, wave-private h1
    const int wave = threadIdx.x >> 6, lane = threadIdx.x & 63;
    const int wbase = blockIdx.x*64 + wave*16;
    ushort (*Sw)[136] = S[wave];

    const int m = lane & 15, quad = lane >> 4;
    int r = wbase + m; if (r >= N) r = N - 1;
    const ushort* ap  = aggb + (size_t)r*FDIM + quad*8;
    const ushort* xp  = xb   + (size_t)r*FDIM + quad*8;
    const ushort* w1p = Wb1  + (size_t)m*256 + quad*8;

    f32x4 acc[8];
    #pragma unroll
    for (int nt = 0; nt < 8; nt++) acc[nt] = f32x4{0.f,0.f,0.f,0.f};
    #pragma unroll
    for (int kt = 0; kt < 8; kt++){
        const int kk = kt*32;
        bf16x8 af = (kk < 128) ? *(const bf16x8*)(ap + kk)
                               : *(const bf16x8*)(xp + (kk - 128));
        #pragma unroll
        for (int nt = 0; nt < 8; nt++){
            bf16x8 bfr = *(const bf16x8*)(w1p + (size_t)nt*16*256 + kk);
            acc[nt] = __builtin_amdgcn_mfma_f32_16x16x32_bf16(af, bfr, acc[nt], 0, 0, 0);
        }
    }
    #pragma unroll
    for (int nt = 0; nt < 8; nt++){
        float b = b1[nt*16 + m];
        acc[nt][0]+=b; acc[nt][1]+=b; acc[nt][2]+=b; acc[nt][3]+=b;
    }
    #pragma unroll
    for (int reg = 0; reg < 4; reg++){
        float ss = 0.f;
        #pragma unroll
        for (int nt = 0; nt < 8; nt++) ss += acc[nt][reg]*acc[nt][reg];
        ss += __shfl_xor(ss,1); ss += __shfl_xor(ss,2); ss += __shfl_xor(ss,4); ss += __shfl_xor(ss,8);
        float invn = 1.f / fmaxf(sqrtf(ss), 1e-12f);
        #pragma unroll
        for (int nt = 0; nt < 8; nt++) acc[nt][reg] = fmaxf(acc[nt][reg]*invn, 0.f);
    }

    // h1 (C-layout) -> LDS [row][col] bf16
    #pragma unroll
    for (int reg = 0; reg < 4; reg++){
        int row = quad*4 + reg;
        #pragma unroll
        for (int nt = 0; nt < 8; nt++) Sw[row][m + nt*16] = f2bf(acc[nt][reg]);
    }
    __syncthreads();

    // mid: [x | h1] @ Wbm^T, relu
    const ushort* wmp = Wbm + (size_t)m*256 + quad*8;
    f32x4 acc2[8];
    #pragma unroll
    for (int nt = 0; nt < 8; nt++) acc2[nt] = f32x4{0.f,0.f,0.f,0.f};
    #pragma unroll
    for (int kt = 0; kt < 8; kt++){
        const int kk = kt*32;
        bf16x8 af = (kk < 128) ? *(const bf16x8*)(xp + kk)
                               : *(const bf16x8*)&Sw[m][(kk - 128) + quad*8];
        #pragma unroll
        for (int nt = 0; nt < 8; nt++){
            bf16x8 bfr = *(const bf16x8*)(wmp + (size_t)nt*16*256 + kk);
            acc2[nt] = __builtin_amdgcn_mfma_f32_16x16x32_bf16(af, bfr, acc2[nt], 0, 0, 0);
        }
    }
    #pragma unroll
    for (int reg = 0; reg < 4; reg++){
        int row = wbase + quad*4 + reg;
        if (row < N){
            ushort* o = hb + (size_t)row*FDIM + m;
            #pragma unroll
            for (int nt = 0; nt < 8; nt++){
                float v = fmaxf(acc2[nt][reg] + bm[nt*16 + m], 0.f);
                o[nt*16] = f2bf(v);
            }
        }
    }
}

// ---------------- MFMA dual-input linear (layer 2), 2 row-tiles per wave ----------------

template<int NOUT, bool NORM, bool RELU, bool OUTF32>
__global__ __launch_bounds__(256) void k_mfma_linear(
    const ushort* __restrict__ A1, const ushort* __restrict__ A2,
    const ushort* __restrict__ Wb, const float* __restrict__ bias,
    void* __restrict__ outv, int N)
{
    constexpr int NT = NOUT / 16;
    constexpr int RT = 2;
    const int lane = threadIdx.x & 63;
    const int wid  = threadIdx.x >> 6;
    const int rowbase = blockIdx.x*(64*RT) + wid*(16*RT);
    if (rowbase >= N) return;
    const int m = lane & 15, quad = lane >> 4;

    const ushort* a1p[RT];
    const ushort* a2p[RT];
    #pragma unroll
    for (int rt = 0; rt < RT; rt++){
        int r = rowbase + rt*16 + m; if (r >= N) r = N - 1;
        a1p[rt] = A1 + (size_t)r*FDIM + quad*8;
        a2p[rt] = A2 + (size_t)r*FDIM + quad*8;
    }
    const ushort* wp = Wb + (size_t)m*256 + quad*8;

    f32x4 acc[RT][NT];
    #pragma unroll
    for (int rt = 0; rt < RT; rt++)
        #pragma unroll
        for (int nt = 0; nt < NT; nt++) acc[rt][nt] = f32x4{0.f,0.f,0.f,0.f};

    #pragma unroll
    for (int kt = 0; kt < 8; kt++){
        const int kk = kt * 32;
        bf16x8 af[RT];
        #pragma unroll
        for (int rt = 0; rt < RT; rt++)
            af[rt] = (kk < 128) ? *(const bf16x8*)(a1p[rt] + kk)
                                : *(const bf16x8*)(a2p[rt] + (kk - 128));
        #pragma unroll
        for (int nt = 0; nt < NT; nt++){
            bf16x8 bfr = *(const bf16x8*)(wp + (size_t)nt*16*256 + kk);
            #pragma unroll
            for (int rt = 0; rt < RT; rt++)
                acc[rt][nt] = __builtin_amdgcn_mfma_f32_16x16x32_bf16(af[rt], bfr, acc[rt][nt], 0, 0, 0);
        }
    }

    #pragma unroll
    for (int rt = 0; rt < RT; rt++){
        #pragma unroll
        for (int nt = 0; nt < NT; nt++){
            float b = bias[nt*16 + m];
            acc[rt][nt][0] += b; acc[rt][nt][1] += b; acc[rt][nt][2] += b; acc[rt][nt][3] += b;
        }
        if (NORM){
            #pragma unroll
            for (int reg = 0; reg < 4; reg++){
                float ss = 0.f;
                #pragma unroll
                for (int nt = 0; nt < NT; nt++) ss += acc[rt][nt][reg] * acc[rt][nt][reg];
                ss += __shfl_xor(ss, 1); ss += __shfl_xor(ss, 2);
                ss += __shfl_xor(ss, 4); ss += __shfl_xor(ss, 8);
                float invn = 1.f / fmaxf(sqrtf(ss), 1e-12f);
                #pragma unroll
                for (int nt = 0; nt < NT; nt++) acc[rt][nt][reg] *= invn;
            }
        }
        if (RELU){
            #pragma unroll
            for (int nt = 0; nt < NT; nt++){
                acc[rt][nt][0] = fmaxf(acc[rt][nt][0], 0.f); acc[rt][nt][1] = fmaxf(acc[rt][nt][1], 0.f);
                acc[rt][nt][2] = fmaxf(acc[rt][nt][2], 0.f); acc[rt][nt][3] = fmaxf(acc[rt][nt][3], 0.f);
            }
        }
        #pragma unroll
        for (int reg = 0; reg < 4; reg++){
            int row = rowbase + rt*16 + quad*4 + reg;
            if (row < N){
                if (OUTF32){
                    float* o = (float*)outv + (size_t)row*NOUT + m;
                    #pragma unroll
                    for (int nt = 0; nt < NT; nt++) o[nt*16] = acc[rt][nt][reg];
                } else {
                    ushort* o = (ushort*)outv + (size_t)row*NOUT + m;
                    #pragma unroll
                    for (int nt = 0; nt < NT; nt++) o[nt*16] = f2bf(acc[rt][nt][reg]);
                }
            }
        }
    }
}

// ---------------- launch ----------------

extern "C" void kernel_launch(void* const* d_in, const int* in_sizes, int n_in,
                              void* d_out, int out_size, void* d_ws, size_t ws_size,
                              hipStream_t stream)
{
    const float* x    = (const float*)d_in[0];
    const int*   ei   = (const int*)  d_in[1];
    const float* W1_l = (const float*)d_in[2];
    const float* b1_l = (const float*)d_in[3];
    const float* W1_r = (const float*)d_in[4];
    const float* Wl1  = (const float*)d_in[5];
    const float* bl1  = (const float*)d_in[6];
    const float* W2_l = (const float*)d_in[7];
    const float* b2_l = (const float*)d_in[8];
    const float* W2_r = (const float*)d_in[9];
    float* out = (float*)d_out;

    const int N = in_sizes[0] / FDIM;   // 50000
    const int E = in_sizes[1] / 2;      // 800000

    const int* src = ei;
    const int* dst = ei + E;

    char* p = (char*)d_ws;
    auto carve = [&](size_t bytes) -> void* {
        void* r = (void*)p;
        p += (bytes + 255) & ~(size_t)255;
        return r;
    };
    int*    deg     = (int*)   carve((size_t)N * 4);
    int*    partial = (int*)   carve((size_t)N * 4);
    int*    bsum    = (int*)   carve(256 * 4);
    int*    off     = (int*)   carve((size_t)N * 4);
    int*    rank    = (int*)   carve((size_t)E * 4);
    int*    csr     = (int*)   carve((size_t)E * 4);
    ushort* xb      = (ushort*)carve((size_t)N * FDIM * 2);
    ushort* hb      = (ushort*)carve((size_t)N * FDIM * 2);
    ushort* aggb    = (ushort*)carve((size_t)N * FDIM * 2);
    ushort* Wb1     = (ushort*)carve((size_t)128 * 256 * 2);
    ushort* Wbm     = (ushort*)carve((size_t)128 * 256 * 2);
    ushort* Wb2     = (ushort*)carve((size_t)64  * 256 * 2);

    hipMemsetAsync(deg, 0, (size_t)N * 4, stream);

    const int gE    = (E + 255) / 256;
    const int gN    = (N + 255) / 256;
    const int gAgg  = (N + 3) / 4;                    // 4 waves/block, 1 node/wave
    const int gF1   = (N + 63) / 64;                  // 4 waves x 16 rows
    const int gLin  = (N + 127) / 128;                // 4 waves x 32 rows
    const int gCast = (N * FDIM / 4 + 255) / 256;
    const int WINW  = (N + 7) / 8;

    // CSR build (reused by both aggregations)
    k_degree_rank<<<gE, 256, 0, stream>>>(dst, deg, rank, E);
    k_scan1 <<<gN, 256, 0, stream>>>(deg, partial, bsum, N);
    k_scan2 <<<1,  256, 0, stream>>>(bsum, gN);
    k_scan3 <<<gN, 256, 0, stream>>>(partial, deg, bsum, off, N);
    k_fill_win<<<512, 256, 0, stream>>>(src, dst, rank, off, csr, E, WINW);

    // bf16 conversions
    k_cast_bf16<<<gCast, 256, 0, stream>>>(x, xb, N * FDIM);
    k_build_w3<<<320, 256, 0, stream>>>(W1_l, W1_r, Wl1, W2_l, W2_r, Wb1, Wbm, Wb2);

    // layer 1 + mid
    k_aggregate_bf16<<<gAgg, 256, 0, stream>>>(xb, csr, off, deg, aggb, N);
    k_lin1mid<<<gF1, 256, 0, stream>>>(aggb, xb, Wb1, b1_l, Wbm, bl1, hb, N);

    // layer 2
    k_aggregate_bf16<<<gAgg, 256, 0, stream>>>(hb, csr, off, deg, aggb, N);
    k_mfma_linear<64, true, false, true><<<gLin, 256, 0, stream>>>(aggb, hb, Wb2, b2_l, out, N);
}